// Round 5
// baseline (247.987 us; speedup 1.0000x reference)
//
#include <hip/hip_runtime.h>
#include <cstdint>
#include <cstddef>

#define NTH 256
#define NGT 128
#define BATCH 16
#define NC 80
#define G 16                  // GTs per scan block
#define NCHUNK (NGT / G)      // 8
#define HW0 25600
#define HW1 6400
#define HW2 1600
#define SL0 4                 // hw slices for level 0
#define MAXSL 4
#define NLOSS_BLK (3 * BATCH * NGT / 4)   // 1536 loss blocks (4 GTs each)

// ws layout (bytes)
#define PART_OFF   0
#define PART_BYTES (3 * BATCH * NGT * MAXSL * 8)          // 196,608
#define PARTL_OFF  PART_BYTES
#define PARTL_BYTES (NLOSS_BLK * 3 * (int)sizeof(float))  // 18,432
#define CNT_OFF    (PARTL_OFF + PARTL_BYTES)

__device__ __forceinline__ unsigned long long umin64(unsigned long long a, unsigned long long b) {
    return a < b ? a : b;
}

#define EVAL(px, py, idx_) do {                                                   \
    _Pragma("unroll")                                                             \
    for (int g = 0; g < G; ++g) {                                                 \
        float dx = gx[g] - (px), dy = gy[g] - (py);                               \
        float d2 = dx * dx + dy * dy;                                             \
        unsigned long long key =                                                  \
            ((unsigned long long)__float_as_uint(d2) << 32) | (unsigned)(idx_);   \
        kmin[g] = umin64(kmin[g], key);                                           \
    } } while (0)

// Scan: one block per (level, batch, hw-slice, chunk-of-16-GTs). Reads raw
// reg rows as float4 (fully coalesced, 16 B/lane; zw discarded — rows are
// L2-resident so the extra bytes are free; scan is VALU-bound at ~7 inst/eval).
// u64 key (d2 bits << 32 | idx): min == min-d2 with first-index tie-break,
// exactly matching jnp.argmin. Block 0 also zeroes the loss completion
// counter (visible to loss_kernel via the kernel-boundary release).
__global__ __launch_bounds__(NTH) void scan_kernel(
    const float4* __restrict__ reg0, const float4* __restrict__ reg1, const float4* __restrict__ reg2,
    const float* __restrict__ gt_boxes,
    unsigned long long* __restrict__ part, unsigned int* __restrict__ counter)
{
    if (blockIdx.x == 0 && threadIdx.x == 0) *counter = 0u;

    int x = blockIdx.x;
    int lvl, b, slice, chunk, HW, nsl;
    const float4* src;
    if (x < BATCH * SL0 * NCHUNK) {                         // 512 lvl-0 blocks
        lvl = 0; b = x / (SL0 * NCHUNK);
        int r = x % (SL0 * NCHUNK);
        slice = r / NCHUNK; chunk = r % NCHUNK;
        HW = HW0; nsl = SL0; src = reg0;
    } else if (x < BATCH * SL0 * NCHUNK + BATCH * NCHUNK) { // 128 lvl-1 blocks
        int y = x - BATCH * SL0 * NCHUNK;
        lvl = 1; b = y / NCHUNK; chunk = y % NCHUNK; slice = 0;
        HW = HW1; nsl = 1; src = reg1;
    } else {                                                // 128 lvl-2 blocks
        int y = x - BATCH * SL0 * NCHUNK - BATCH * NCHUNK;
        lvl = 2; b = y / NCHUNK; chunk = y % NCHUNK; slice = 0;
        HW = HW2; nsl = 1; src = reg2;
    }

    const int seg = HW / nsl;
    const int e0 = slice * seg, e1 = e0 + seg;
    const int tid = threadIdx.x, wave = tid >> 6, lane = tid & 63;
    const int n0 = chunk * G;

    float gx[G], gy[G];
#pragma unroll
    for (int g = 0; g < G; ++g) {
        const float* gb = gt_boxes + (size_t)(b * NGT + n0 + g) * 4;
        gx[g] = gb[0]; gy[g] = gb[1];
    }

    unsigned long long kmin[G];
#pragma unroll
    for (int g = 0; g < G; ++g) kmin[g] = ~0ull;

    const float4* base = src + (size_t)b * HW;
    for (int i = e0 + tid; i < e1; i += NTH) {
        float4 p = base[i];
        EVAL(p.x, p.y, i);
    }

#pragma unroll
    for (int g = 0; g < G; ++g) {
#pragma unroll
        for (int off = 32; off >= 1; off >>= 1) {
            unsigned long long o = __shfl_down(kmin[g], off, 64);
            kmin[g] = umin64(kmin[g], o);
        }
    }

    __shared__ unsigned long long smem[G][4];
    if (lane == 0) {
#pragma unroll
        for (int g = 0; g < G; ++g) smem[g][wave] = kmin[g];
    }
    __syncthreads();

    if (tid < G) {
        unsigned long long key = umin64(umin64(smem[tid][0], smem[tid][1]),
                                        umin64(smem[tid][2], smem[tid][3]));
        part[((size_t)(lvl * BATCH + b) * NGT + n0 + tid) * MAXSL + slice] = key;
    }
}

// Loss: one wave per (level, batch, gt); 4 waves per block. No same-address
// atomics (R3 lesson: 18K serialized RMWs = 239 us). Each block writes one
// partial triple; the LAST block (device-scope counter + release/acquire
// fences, rocPRIM-style) tree-reduces all 1536 triples in a fixed
// deterministic order and writes the 3 outputs.
__global__ __launch_bounds__(NTH) void loss_kernel(
    const float* __restrict__ cls0, const float* __restrict__ cls1, const float* __restrict__ cls2,
    const float* __restrict__ reg0, const float* __restrict__ reg1, const float* __restrict__ reg2,
    const float* __restrict__ gt_boxes, const int* __restrict__ gt_labels,
    const unsigned long long* __restrict__ part, float* __restrict__ partl,
    unsigned int* __restrict__ counter, float* __restrict__ out)
{
    const int wave = threadIdx.x >> 6;
    const int lane = threadIdx.x & 63;
    const int gid = blockIdx.x * 4 + wave;     // 0..6143
    const int lvl = gid / (BATCH * NGT);
    const int r = gid % (BATCH * NGT);
    const int b = r / NGT, n = r % NGT;

    const float* cls; const float* reg; int HW, S;
    if (lvl == 0)      { cls = cls0; reg = reg0; HW = HW0; S = SL0; }
    else if (lvl == 1) { cls = cls1; reg = reg1; HW = HW1; S = 1; }
    else               { cls = cls2; reg = reg2; HW = HW2; S = 1; }

    const unsigned long long* p = part + (size_t)gid * MAXSL;
    unsigned long long key = p[0];
    for (int s = 1; s < S; ++s) key = umin64(key, p[s]);

    int match = (int)(unsigned)(key & 0xffffffffu);
    float d2min = __uint_as_float((unsigned)(key >> 32));
    bool valid = d2min < 6.25f;  // sqrt(d2) < 2.5

    const int label = gt_labels[b * NGT + n];
    const float* c = cls + ((size_t)b * HW + match) * NC;

    // 80-class log-softmax across the wave
    float x1 = c[lane];
    float x2 = (lane < NC - 64) ? c[64 + lane] : -INFINITY;
    float mx = fmaxf(x1, x2);
#pragma unroll
    for (int off = 32; off >= 1; off >>= 1) mx = fmaxf(mx, __shfl_xor(mx, off, 64));
    float s = expf(x1 - mx) + ((lane < NC - 64) ? expf(x2 - mx) : 0.0f);
#pragma unroll
    for (int off = 32; off >= 1; off >>= 1) s += __shfl_xor(s, off, 64);

    __shared__ float ce_s[4], l1_s[4], w_s[4];
    __shared__ int is_last;
    if (lane == 0) {
        float ce = 0.0f, l1 = 0.0f, w = 0.0f;
        if (valid) {
            float xlab = c[label];
            ce = -(xlab - mx - logf(s));
            const float* gb = gt_boxes + (size_t)(b * NGT + n) * 4;
            const float* gr = reg + ((size_t)b * HW + match) * 4;
            l1 = fabsf(gr[0] - gb[0]) + fabsf(gr[1] - gb[1]) +
                 fabsf(gr[2] - gb[2]) + fabsf(gr[3] - gb[3]);
            w = 1.0f;
        }
        ce_s[wave] = ce; l1_s[wave] = l1; w_s[wave] = w;
    }
    __syncthreads();

    if (threadIdx.x == 0) {
        float* o = partl + (size_t)blockIdx.x * 3;
        o[0] = ce_s[0] + ce_s[1] + ce_s[2] + ce_s[3];
        o[1] = l1_s[0] + l1_s[1] + l1_s[2] + l1_s[3];
        o[2] = w_s[0] + w_s[1] + w_s[2] + w_s[3];
        __threadfence();                         // release: drain partl to coherent point
        unsigned int old = atomicAdd(counter, 1u);  // device-scope RMW
        is_last = (old == (unsigned)(NLOSS_BLK - 1));
    }
    __syncthreads();

    if (is_last) {
        __threadfence();                         // acquire: invalidate stale cached lines
        const int tid = threadIdx.x;
        float ce = 0.0f, l1 = 0.0f, w = 0.0f;
        for (int i = tid; i < NLOSS_BLK; i += NTH) {
            ce += partl[(size_t)i * 3 + 0];
            l1 += partl[(size_t)i * 3 + 1];
            w  += partl[(size_t)i * 3 + 2];
        }
#pragma unroll
        for (int off = 32; off >= 1; off >>= 1) {
            ce += __shfl_xor(ce, off, 64);
            l1 += __shfl_xor(l1, off, 64);
            w  += __shfl_xor(w,  off, 64);
        }
        __shared__ float sm[3][4];
        if (lane == 0) { sm[0][wave] = ce; sm[1][wave] = l1; sm[2][wave] = w; }
        __syncthreads();
        if (tid == 0) {
            float tce = sm[0][0] + sm[0][1] + sm[0][2] + sm[0][3];
            float tl1 = sm[1][0] + sm[1][1] + sm[1][2] + sm[1][3];
            float tw  = sm[2][0] + sm[2][1] + sm[2][2] + sm[2][3];
            float denom = fmaxf(tw, 1.0f);
            out[0] = tce / denom;
            out[1] = tl1 / denom;
            out[2] = tw;
        }
    }
}

extern "C" void kernel_launch(void* const* d_in, const int* in_sizes, int n_in,
                              void* d_out, int out_size, void* d_ws, size_t ws_size,
                              hipStream_t stream) {
    // Map inputs BY SIZE (dict order interleaves cls/reg; all sizes distinct).
    const float* cls0 = nullptr; const float* cls1 = nullptr; const float* cls2 = nullptr;
    const float* reg0 = nullptr; const float* reg1 = nullptr; const float* reg2 = nullptr;
    const float* gt_boxes = nullptr; const int* gt_labels = nullptr;
    for (int i = 0; i < n_in; ++i) {
        switch (in_sizes[i]) {
            case BATCH * HW0 * NC: cls0 = (const float*)d_in[i]; break;
            case BATCH * HW1 * NC: cls1 = (const float*)d_in[i]; break;
            case BATCH * HW2 * NC: cls2 = (const float*)d_in[i]; break;
            case BATCH * HW0 * 4:  reg0 = (const float*)d_in[i]; break;
            case BATCH * HW1 * 4:  reg1 = (const float*)d_in[i]; break;
            case BATCH * HW2 * 4:  reg2 = (const float*)d_in[i]; break;
            case BATCH * NGT * 4:  gt_boxes = (const float*)d_in[i]; break;
            case BATCH * NGT:      gt_labels = (const int*)d_in[i]; break;
            default: break;
        }
    }

    char* ws = (char*)d_ws;
    unsigned long long* part = (unsigned long long*)(ws + PART_OFF);
    float* partl = (float*)(ws + PARTL_OFF);
    unsigned int* counter = (unsigned int*)(ws + CNT_OFF);

    const int scan_grid = BATCH * SL0 * NCHUNK + 2 * BATCH * NCHUNK;  // 768
    scan_kernel<<<scan_grid, NTH, 0, stream>>>(
        (const float4*)reg0, (const float4*)reg1, (const float4*)reg2,
        gt_boxes, part, counter);

    loss_kernel<<<NLOSS_BLK, NTH, 0, stream>>>(
        cls0, cls1, cls2, reg0, reg1, reg2, gt_boxes, gt_labels,
        part, partl, counter, (float*)d_out);
}